// Round 10
// baseline (161.628 us; speedup 1.0000x reference)
//
#include <hip/hip_runtime.h>
#include <stdint.h>

#define Bn 4
#define An 3
#define Hn 168
#define Wn 256
#define Mn 32
#define HWn (Hn*Wn)
#define Nn (HWn*An)          // 129024
#define POS_CAP 8192
#define BND_CAP 2048
#define NPERIM 256
#define NPOSMAX 128
#define FG_THR 0.7f
#define BG_THR 0.3f
#define BETA (1.0f/9.0f)

#define NBLK 126             // blocks per image
#define APT 4                // anchors/thread (measured best)
#define STRIDE (NBLK * 256)  // 32256
#define SEG 1024             // NLIST segment per block (== anchors/block, no overflow)
#define WPI (NBLK * 4)       // waves per image = 504

// ---- workspace layout (uint32 word offsets) ----
#define OFF_POSCNT 0            // Bn
#define OFF_BNDCNT 4            // Bn
#define OFF_BOUND  8            // Bn
#define OFF_NEED   12           // Bn
#define OFF_COUNT  16           // 1
#define OFF_CLS    17           // 1 (float bits)
#define OFF_REG    18           // 1 (float bits)
#define OFF_DONE   19           // 1
#define OFF_KEYS   24           // Bn*2
#define OFF_WMAX   32           // Bn*WPI*Mn = 64512        -> 64544  (per-wave colmax, float bits)
#define OFF_PACKED 64544        // Bn*Nn*2 = 1032192        -> 1096736 (eqmask + flags per anchor)
#define OFF_NSEGC  1096736      // Bn*NBLK = 504            -> 1097240
#define OFF_PHIST  1097240      // Bn*NBLK*1024 = 516096    -> 1613336
#define OFF_PLIST  1613336      // Bn*POS_CAP*2             -> 1678872
#define OFF_BLIST  1678872      // Bn*BND_CAP*2             -> 1695256
#define OFF_NLIST  1695256      // Bn*NBLK*SEG*2 = 1032192  -> 2727448 (~10.9MB)

// ------------------- threefry2x32 (20 rounds) -------------------
__device__ __forceinline__ uint32_t rotl32(uint32_t v, int n) { return (v << n) | (v >> (32 - n)); }

__device__ __forceinline__ void tf2x32(uint32_t k0, uint32_t k1, uint32_t x0, uint32_t x1,
                                       uint32_t& o0, uint32_t& o1) {
    uint32_t k2 = k0 ^ k1 ^ 0x1BD11BDAu;
    x0 += k0; x1 += k1;
    x0 += x1; x1 = rotl32(x1, 13); x1 ^= x0;
    x0 += x1; x1 = rotl32(x1, 15); x1 ^= x0;
    x0 += x1; x1 = rotl32(x1, 26); x1 ^= x0;
    x0 += x1; x1 = rotl32(x1, 6);  x1 ^= x0;
    x0 += k1; x1 += k2 + 1u;
    x0 += x1; x1 = rotl32(x1, 17); x1 ^= x0;
    x0 += x1; x1 = rotl32(x1, 29); x1 ^= x0;
    x0 += x1; x1 = rotl32(x1, 16); x1 ^= x0;
    x0 += x1; x1 = rotl32(x1, 24); x1 ^= x0;
    x0 += k2; x1 += k0 + 2u;
    x0 += x1; x1 = rotl32(x1, 13); x1 ^= x0;
    x0 += x1; x1 = rotl32(x1, 15); x1 ^= x0;
    x0 += x1; x1 = rotl32(x1, 26); x1 ^= x0;
    x0 += x1; x1 = rotl32(x1, 6);  x1 ^= x0;
    x0 += k0; x1 += k1 + 3u;
    x0 += x1; x1 = rotl32(x1, 17); x1 ^= x0;
    x0 += x1; x1 = rotl32(x1, 29); x1 ^= x0;
    x0 += x1; x1 = rotl32(x1, 16); x1 ^= x0;
    x0 += x1; x1 = rotl32(x1, 24); x1 ^= x0;
    x0 += k1; x1 += k2 + 4u;
    x0 += x1; x1 = rotl32(x1, 13); x1 ^= x0;
    x0 += x1; x1 = rotl32(x1, 15); x1 ^= x0;
    x0 += x1; x1 = rotl32(x1, 26); x1 ^= x0;
    x0 += x1; x1 = rotl32(x1, 6);  x1 ^= x0;
    x0 += k2; x1 += k0 + 5u;
    o0 = x0; o1 = x1;
}

__device__ __forceinline__ uint32_t rng_m23(uint32_t k0, uint32_t k1, uint32_t i) {
    uint32_t o0, o1;
    tf2x32(k0, k1, 0u, i, o0, o1);
    return (o0 ^ o1) >> 9;
}

// ------------------- IoU -------------------
__device__ __forceinline__ float iou_one(float a0, float a1, float a2, float a3,
                                         float t0, float t1, float t2, float t3) {
    float xtl = fmaxf(a0, t0), ytl = fmaxf(a1, t1);
    float xrb = fminf(a2, t2), yrb = fminf(a3, t3);
    float iw = fmaxf(xrb - xtl + 1.0f, 0.0f);
    float ih = fmaxf(yrb - ytl + 1.0f, 0.0f);
    float inter = iw * ih;
    float area1 = (a2 - a0 + 1.0f) * (a3 - a1 + 1.0f);
    float area2 = (t2 - t0 + 1.0f) * (t3 - t1 + 1.0f);
    return inter * __builtin_amdgcn_rcpf(area1 + area2 - inter);
}

// ------------------- K1: single IoU pass -------------------
// Per anchor emits 8B: eqmask (bit t: iou == my wave's max for target t),
// ori, inside, rowmax-class bits. Per wave emits wavemax[32]. Restore is
// recovered EXACTLY in k2 via iou==colmax <=> (eqbit && wavemax==colmax).
__global__ void __launch_bounds__(256) k1_colmax(const float* __restrict__ anchors,
                                                 const float* __restrict__ targets,
                                                 const float* __restrict__ sizes,
                                                 uint32_t* __restrict__ ws) {
    int b = blockIdx.y, j = blockIdx.x, tid = threadIdx.x;
    if (b == 0 && j == 0) {    // folded init (visible to k2 via launch order)
        if (tid < 24) ws[tid] = 0u;
        if (tid == 0) {
            for (int bb = 0; bb < Bn; ++bb) {
                uint32_t o0, o1;
                tf2x32(0u, 42u, 0u, (uint32_t)bb, o0, o1);
                ws[OFF_KEYS + 2*bb] = o0; ws[OFF_KEYS + 2*bb + 1] = o1;
            }
        }
    }
    int lane = tid & 63;
    int w = j * 4 + (tid >> 6);          // wave index within image
    int base = j * 256 + tid;
    float4 a[APT];
    #pragma unroll
    for (int k = 0; k < APT; ++k)
        a[k] = ((const float4*)anchors)[b * Nn + base + k * STRIDE];
    float rowmax[APT]; int ori[APT]; uint32_t eqm[APT];
    #pragma unroll
    for (int k = 0; k < APT; ++k) { rowmax[k] = -1.0f; ori[k] = 0; eqm[k] = 0u; }
    float mywm = 0.0f;                   // lane<32: wavemax for target t==lane
    #pragma unroll 4
    for (int t = 0; t < Mn; ++t) {
        float4 tv = ((const float4*)targets)[b * Mn + t];
        float iou[APT];
        float m0 = 0.0f;
        #pragma unroll
        for (int k = 0; k < APT; ++k) {
            iou[k] = iou_one(a[k].x, a[k].y, a[k].z, a[k].w, tv.x, tv.y, tv.z, tv.w);
            if (iou[k] > rowmax[k]) { rowmax[k] = iou[k]; ori[k] = t; }
            m0 = fmaxf(m0, iou[k]);
        }
        #pragma unroll
        for (int o = 32; o > 0; o >>= 1) m0 = fmaxf(m0, __shfl_xor(m0, o, 64));
        #pragma unroll
        for (int k = 0; k < APT; ++k)
            eqm[k] |= (iou[k] == m0) ? (1u << t) : 0u;
        mywm = (lane == t) ? m0 : mywm;
    }
    if (lane < Mn)
        ws[OFF_WMAX + ((size_t)b * WPI + w) * Mn + lane] = __float_as_uint(mywm);
    float sh = sizes[b * 2 + 0], sw = sizes[b * 2 + 1];
    #pragma unroll
    for (int k = 0; k < APT; ++k) {
        int i = base + k * STRIDE;
        uint32_t inside = (a[k].x >= 0.0f) && (a[k].y >= 0.0f) &&
                          (a[k].z <= sw - 1.0f) && (a[k].w <= sh - 1.0f);
        uint32_t flags = (uint32_t)ori[k] | (inside << 5) |
                         ((rowmax[k] >= FG_THR ? 1u : 0u) << 6) |
                         ((rowmax[k] <  BG_THR ? 1u : 0u) << 7);
        ((uint2*)(ws + OFF_PACKED))[(size_t)b * Nn + i] = make_uint2(eqm[k], flags);
    }
}

// ------------------- K2: categorize (no IoU) + RNG + hist + compacted lists ---------
__global__ void __launch_bounds__(256) k2_cat(uint32_t* __restrict__ ws) {
    int b = blockIdx.y, j = blockIdx.x, tid = threadIdx.x;
    int lane = tid & 63;
    int w = j * 4 + (tid >> 6);
    __shared__ float cmf[Mn];
    __shared__ float redf[256];
    __shared__ uint32_t lh[1024];
    __shared__ uint32_t segcnt;
    // prologue: colmax = max over the image's 504 wave records (exact)
    {
        int t = tid & 31, sub = tid >> 5;
        float acc = 0.0f;
        for (int ww = sub; ww < WPI; ww += 8)
            acc = fmaxf(acc, __uint_as_float(ws[OFF_WMAX + ((size_t)b * WPI + ww) * Mn + t]));
        redf[tid] = acc;
        __syncthreads();
        if (sub == 0) {
            #pragma unroll
            for (int q = 1; q < 8; ++q) acc = fmaxf(acc, redf[t + 32 * q]);
            cmf[t] = acc;
        }
    }
    #pragma unroll
    for (int q = 0; q < 4; ++q) lh[tid + 256 * q] = 0u;
    if (tid == 0) segcnt = 0u;
    __syncthreads();
    // per-wave gmask: bit t set iff my wave's max equals global colmax for t
    float wmv = (lane < Mn)
        ? __uint_as_float(ws[OFF_WMAX + ((size_t)b * WPI + w) * Mn + lane]) : -1.0f;
    float cmv = (lane < Mn) ? cmf[lane] : 0.0f;
    uint32_t gmask = (uint32_t)__ballot(lane < Mn && wmv == cmv);

    uint32_t key0 = ws[OFF_KEYS + 2 * b], key1 = ws[OFF_KEYS + 2 * b + 1];
    unsigned long long lt_mask = (lane == 63) ? 0x7FFFFFFFFFFFFFFFull : ((1ull << lane) - 1ull);
    uint2* nseg = (uint2*)(ws + OFF_NLIST) + (size_t)(b * NBLK + j) * SEG;
    int base = j * 256 + tid;
    #pragma unroll
    for (int k = 0; k < APT; ++k) {
        int i = base + k * STRIDE;
        uint2 pk = ((const uint2*)(ws + OFF_PACKED))[(size_t)b * Nn + i];
        uint32_t ori = pk.y & 31u;
        bool inside = (pk.y >> 5) & 1u;
        bool gefg   = (pk.y >> 6) & 1u;
        bool ltbg   = (pk.y >> 7) & 1u;
        bool restore = (pk.x & gmask) != 0u;
        uint32_t cat = 0;
        if (inside) {
            if (restore || gefg) cat = 2;
            else if (ltbg) cat = 1;
        }
        uint32_t m = rng_m23(key0, key1, (uint32_t)i);
        unsigned long long pmask = __ballot(cat == 2u);     // rare -> cheap
        if (pmask) {
            int leader = __ffsll((long long)pmask) - 1;
            uint32_t bb = 0;
            if (lane == leader) bb = atomicAdd(&ws[OFF_POSCNT + b], (uint32_t)__popcll(pmask));
            bb = __shfl(bb, leader, 64);
            if (cat == 2u) {
                uint32_t p = bb + (uint32_t)__popcll(pmask & lt_mask);
                if (p < POS_CAP)
                    ((uint2*)(ws + OFF_PLIST))[(size_t)b * POS_CAP + p] =
                        make_uint2(m, (uint32_t)i | (ori << 17));
            }
        }
        unsigned long long nmask = __ballot(cat == 1u);     // LDS counter only
        if (nmask) {
            int leader = __ffsll((long long)nmask) - 1;
            uint32_t bb = 0;
            if (lane == leader) bb = atomicAdd(&segcnt, (uint32_t)__popcll(nmask));
            bb = __shfl(bb, leader, 64);
            if (cat == 1u) {
                uint32_t p = bb + (uint32_t)__popcll(nmask & lt_mask);
                nseg[p] = make_uint2(m, (uint32_t)i);
                atomicAdd(&lh[m >> 13], 1u);
            }
        }
    }
    __syncthreads();
    uint32_t* slice = ws + OFF_PHIST + ((size_t)b * NBLK + j) * 1024;
    #pragma unroll
    for (int q = 0; q < 4; ++q) slice[tid + 256 * q] = lh[tid + 256 * q];
    if (tid == 0) ws[OFF_NSEGC + b * NBLK + j] = segcnt;
}

// ------------------- K2.5: reduce slices + suffix scan + boundary -------------------
__global__ void __launch_bounds__(256) k25_bound(uint32_t* __restrict__ ws) {
    int b = blockIdx.x, t = threadIdx.x;
    __shared__ uint32_t csum[256];
    uint4 h = make_uint4(0, 0, 0, 0);
    const uint32_t* ph = ws + OFF_PHIST + (size_t)b * NBLK * 1024;
    for (int s = 0; s < NBLK; ++s) {
        uint4 v = ((const uint4*)(ph + (size_t)s * 1024))[t];
        h.x += v.x; h.y += v.y; h.z += v.z; h.w += v.w;
    }
    uint32_t sum = h.x + h.y + h.z + h.w;
    csum[t] = sum;
    __syncthreads();
    for (int off = 1; off < 256; off <<= 1) {
        uint32_t mine = csum[t];
        uint32_t add = (t + off < 256) ? csum[t + off] : 0u;
        __syncthreads();
        csum[t] = mine + add;
        __syncthreads();
    }
    uint32_t pc = ws[OFF_POSCNT + b];
    int num_pos = (pc < (uint32_t)NPOSMAX) ? (int)pc : NPOSMAX;
    int k_neg = NPERIM - num_pos;
    uint32_t total = csum[0];
    if ((int)total < k_neg) {
        if (t == 0) {
            ws[OFF_BOUND + b] = 0xFFFFFFFFu;
            ws[OFF_NEED + b] = 0u;
            atomicAdd(&ws[OFF_COUNT], (uint32_t)(num_pos + (int)total));
        }
        return;
    }
    uint32_t incl = csum[t];
    uint32_t next = (t < 255) ? csum[t + 1] : 0u;
    if ((int)incl >= k_neg && (int)next < k_neg) {
        int cum = (int)next;
        uint32_t hv[4] = { h.x, h.y, h.z, h.w };
        int boundary = -1, needed = 0;
        #pragma unroll
        for (int q = 3; q >= 0; --q) {
            int c = (int)hv[q];
            if (cum + c >= k_neg) { boundary = 4 * t + q; needed = k_neg - cum; break; }
            cum += c;
        }
        ws[OFF_BOUND + b] = (uint32_t)boundary;
        ws[OFF_NEED + b] = (uint32_t)needed;
        atomicAdd(&ws[OFF_COUNT], (uint32_t)(num_pos + k_neg));
    }
}

// ------------------- K3: scan per-block negative segments -------------------
__global__ void __launch_bounds__(256) k3_neg(const float* __restrict__ logits,
                                              uint32_t* __restrict__ ws) {
    int b = blockIdx.y, j = blockIdx.x;
    int bd = (int)(int32_t)ws[OFF_BOUND + b];
    int cnt = (int)ws[OFF_NSEGC + b * NBLK + j];
    const uint2* nseg = (const uint2*)(ws + OFF_NLIST) + (size_t)(b * NBLK + j) * SEG;
    float local = 0.0f;
    for (int idx = (int)threadIdx.x; idx < cnt; idx += 256) {
        uint2 e = nseg[idx];
        int bk = (int)(e.x >> 13);
        if (bk > bd) {
            int i = (int)e.y;
            int a = i % An, hw = i / An;
            float l = logits[(b * An + a) * HWn + hw];
            local += fmaxf(l, 0.0f) + log1pf(expf(-fabsf(l)));   // BCE(l,0)
        } else if (bk == bd) {
            uint32_t q = atomicAdd(&ws[OFF_BNDCNT + b], 1u);    // rare (~100/image)
            if (q < BND_CAP)
                ((uint2*)(ws + OFF_BLIST))[(size_t)b * BND_CAP + q] = e;
        }
    }
    __shared__ float red[256];
    red[threadIdx.x] = local;
    __syncthreads();
    for (int s = 128; s > 0; s >>= 1) {
        if ((int)threadIdx.x < s) red[threadIdx.x] += red[threadIdx.x + s];
        __syncthreads();
    }
    if (threadIdx.x == 0 && red[0] != 0.0f) atomicAdd((float*)&ws[OFF_CLS], red[0]);
}

// ------------------- K4: per-image finalize + output -------------------
__device__ __forceinline__ bool sel_less(uint2 a, uint2 b) {
    return (a.x > b.x) || (a.x == b.x && a.y < b.y);
}

__device__ void bitonic_sort_shared(uint2* buf, int n) {   // n = pow2
    for (int k = 2; k <= n; k <<= 1) {
        for (int j = k >> 1; j > 0; j >>= 1) {
            for (int t = (int)threadIdx.x; t < n; t += 256) {
                int ixj = t ^ j;
                if (ixj > t) {
                    uint2 x = buf[t], y = buf[ixj];
                    bool up = ((t & k) == 0);
                    bool sw = up ? sel_less(y, x) : sel_less(x, y);
                    if (sw) { buf[t] = y; buf[ixj] = x; }
                }
            }
            __syncthreads();
        }
    }
}

__global__ void __launch_bounds__(256) k4_final(const float* __restrict__ anchors,
                                                const float* __restrict__ targets,
                                                const float* __restrict__ logits,
                                                const float* __restrict__ bregs,
                                                uint32_t* __restrict__ ws,
                                                float* __restrict__ out) {
    int b = blockIdx.x, tid = threadIdx.x;
    __shared__ uint2 buf[BND_CAP];
    __shared__ float red[256];
    float cls = 0.0f, reg = 0.0f;

    uint32_t pcu = ws[OFF_POSCNT + b];
    int pc = (pcu < (uint32_t)POS_CAP) ? (int)pcu : POS_CAP;
    const uint2* plist = (const uint2*)(ws + OFF_PLIST) + (size_t)b * POS_CAP;
    int psel = (pc < NPOSMAX) ? pc : NPOSMAX;
    bool use_buf = false;
    if (pc > NPOSMAX) {
        int n = (pc < BND_CAP) ? pc : BND_CAP;
        for (int t = tid; t < n; t += 256) buf[t] = plist[t];
        int npad = 1; while (npad < n) npad <<= 1;
        for (int t = tid; t < npad; t += 256) if (t >= n) buf[t] = make_uint2(0u, 0xFFFFFFFFu);
        __syncthreads();
        bitonic_sort_shared(buf, npad);
        use_buf = true;
        psel = (NPOSMAX < n) ? NPOSMAX : n;
    }
    for (int t = tid; t < psel; t += 256) {
        uint32_t packed = use_buf ? buf[t].y : plist[t].y;
        int i = (int)(packed & 0x1FFFFu);
        int ori = (int)(packed >> 17);
        int a = i % An, hw = i / An;
        float l = logits[(b * An + a) * HWn + hw];
        cls += fmaxf(l, 0.0f) - l + log1pf(expf(-fabsf(l)));   // BCE(l,1)
        float4 av = ((const float4*)anchors)[b * Nn + i];
        float4 tv = ((const float4*)targets)[b * Mn + ori];
        float aws = av.z - av.x + 1.0f, ahs = av.w - av.y + 1.0f;
        float axc = av.x + 0.5f * aws, ayc = av.y + 0.5f * ahs;
        float tws = tv.z - tv.x + 1.0f, ths = tv.w - tv.y + 1.0f;
        float txc = tv.x + 0.5f * tws, tyc = tv.y + 0.5f * ths;
        float off0 = (txc - axc) / aws;
        float off1 = (tyc - ayc) / ahs;
        float off2 = logf(tws / aws);
        float off3 = logf(ths / ahs);
        float br0 = bregs[(b * 12 + a * 4 + 0) * HWn + hw];
        float br1 = bregs[(b * 12 + a * 4 + 1) * HWn + hw];
        float br2 = bregs[(b * 12 + a * 4 + 2) * HWn + hw];
        float br3 = bregs[(b * 12 + a * 4 + 3) * HWn + hw];
        float d;
        d = fabsf(br0 - off0); reg += (d < BETA) ? 0.5f * d * d / BETA : d - 0.5f * BETA;
        d = fabsf(br1 - off1); reg += (d < BETA) ? 0.5f * d * d / BETA : d - 0.5f * BETA;
        d = fabsf(br2 - off2); reg += (d < BETA) ? 0.5f * d * d / BETA : d - 0.5f * BETA;
        d = fabsf(br3 - off3); reg += (d < BETA) ? 0.5f * d * d / BETA : d - 0.5f * BETA;
    }
    __syncthreads();

    int need = (int)ws[OFF_NEED + b];
    if (need > 0) {
        uint32_t nbu = ws[OFF_BNDCNT + b];
        int nb = (nbu < (uint32_t)BND_CAP) ? (int)nbu : BND_CAP;
        const uint2* blist = (const uint2*)(ws + OFF_BLIST) + (size_t)b * BND_CAP;
        for (int t = tid; t < nb; t += 256) buf[t] = blist[t];
        int npad = 1; while (npad < nb) npad <<= 1;
        for (int t = tid; t < npad; t += 256) if (t >= nb) buf[t] = make_uint2(0u, 0xFFFFFFFFu);
        __syncthreads();
        bitonic_sort_shared(buf, npad);
        int sel = (need < nb) ? need : nb;
        for (int t = tid; t < sel; t += 256) {
            int i = (int)buf[t].y;
            int a = i % An, hw = i / An;
            float l = logits[(b * An + a) * HWn + hw];
            cls += fmaxf(l, 0.0f) + log1pf(expf(-fabsf(l)));   // BCE(l,0)
        }
    }

    red[tid] = cls;
    __syncthreads();
    for (int s = 128; s > 0; s >>= 1) {
        if (tid < s) red[tid] += red[tid + s];
        __syncthreads();
    }
    if (tid == 0 && red[0] != 0.0f) atomicAdd((float*)&ws[OFF_CLS], red[0]);
    __syncthreads();
    red[tid] = reg;
    __syncthreads();
    for (int s = 128; s > 0; s >>= 1) {
        if (tid < s) red[tid] += red[tid + s];
        __syncthreads();
    }
    if (tid == 0) {
        if (red[0] != 0.0f) atomicAdd((float*)&ws[OFF_REG], red[0]);
        __threadfence();
        uint32_t old = atomicAdd(&ws[OFF_DONE], 1u);
        if (old == Bn - 1) {
            float cls_tot = __uint_as_float(atomicAdd(&ws[OFF_CLS], 0u));
            float reg_tot = __uint_as_float(atomicAdd(&ws[OFF_REG], 0u));
            float cnt = (float)atomicAdd(&ws[OFF_COUNT], 0u);
            out[0] = cls_tot / cnt;
            out[1] = reg_tot / cnt;
        }
    }
}

extern "C" void kernel_launch(void* const* d_in, const int* in_sizes, int n_in,
                              void* d_out, int out_size, void* d_ws, size_t ws_size,
                              hipStream_t stream) {
    const float* anchors = (const float*)d_in[0];   // [B, N, 4]
    const float* logits  = (const float*)d_in[1];   // [B, A, H, W]
    const float* bregs   = (const float*)d_in[2];   // [B, 4A, H, W]
    const float* sizes   = (const float*)d_in[3];   // [B, 2]
    const float* targets = (const float*)d_in[4];   // [B, M, 4]
    float* out = (float*)d_out;
    uint32_t* ws = (uint32_t*)d_ws;

    k1_colmax<<<dim3(NBLK, Bn), dim3(256), 0, stream>>>(anchors, targets, sizes, ws);
    k2_cat<<<dim3(NBLK, Bn), dim3(256), 0, stream>>>(ws);
    k25_bound<<<dim3(Bn), dim3(256), 0, stream>>>(ws);
    k3_neg<<<dim3(NBLK, Bn), dim3(256), 0, stream>>>(logits, ws);
    k4_final<<<dim3(Bn), dim3(256), 0, stream>>>(anchors, targets, logits, bregs, ws, out);
}